// Round 1
// baseline (1640.819 us; speedup 1.0000x reference)
//
#include <hip/hip_runtime.h>
#include <math.h>

#define NF 15552      // B*T
#define NJ 17
#define NC 128
#define JC (NJ*NC)    // 2176

constexpr int cA[15] = {0,1,2,0,4,5,0,7,8,0,10,11,0,13,14};
constexpr int cB[15] = {1,2,3,4,5,6,7,8,9,10,11,12,13,14,15};
constexpr int aJ[4] = {11,14,5,8};
constexpr int aP[4] = {10,13,4,7};
constexpr int aCc[4] = {12,15,6,9};

__device__ __forceinline__ float gelu_exact(float x){
  return 0.5f * x * (1.0f + erff(x * 0.7071067811865476f));
}

// ---------------- geometry: actual_angles + actual_bone_lengths ----------------
__global__ __launch_bounds__(256) void k_geom(const float* __restrict__ pose,
                                              float* __restrict__ out_aa,
                                              float* __restrict__ out_abl)
{
  const int f = blockIdx.x * 256 + threadIdx.x;
  if (f >= NF) return;
  const float* p = pose + (long)f * NJ * 3;
  float px[NJ], py[NJ], pz[NJ];
  #pragma unroll
  for (int j = 0; j < NJ; ++j){ px[j] = p[3*j]; py[j] = p[3*j+1]; pz[j] = p[3*j+2]; }

  #pragma unroll
  for (int i = 0; i < 15; ++i){
    const int a = cA[i], b = cB[i];
    const float dx = px[b]-px[a], dy = py[b]-py[a], dz = pz[b]-pz[a];
    out_abl[(long)f*15 + i] = sqrtf(dx*dx + dy*dy + dz*dz);
  }

  float ang[NJ];
  #pragma unroll
  for (int j = 0; j < NJ; ++j) ang[j] = 0.0f;
  #pragma unroll
  for (int i = 0; i < 4; ++i){
    const int jj = aJ[i], pp = aP[i], cc = aCc[i];
    float v1x = px[jj]-px[pp], v1y = py[jj]-py[pp], v1z = pz[jj]-pz[pp];
    float v2x = px[cc]-px[jj], v2y = py[cc]-py[jj], v2z = pz[cc]-pz[jj];
    const float n1 = sqrtf(v1x*v1x + v1y*v1y + v1z*v1z) + 1e-10f;
    const float n2 = sqrtf(v2x*v2x + v2y*v2y + v2z*v2z) + 1e-10f;
    v1x /= n1; v1y /= n1; v1z /= n1;
    v2x /= n2; v2y /= n2; v2z /= n2;
    float d = v1x*v2x + v1y*v2y + v1z*v2z;
    d = fminf(fmaxf(d, -1.0f + 1e-7f), 1.0f - 1e-7f);
    ang[jj] = acosf(d);
  }
  #pragma unroll
  for (int j = 0; j < NJ; ++j) out_aa[(long)f*NJ + j] = ang[j];
}

// ---------------- angle MLP: gelu(f@aw1+ab1)@aw2+ab2 ----------------
#define FPB2 4
__global__ __launch_bounds__(256) void k_angle(const float* __restrict__ feat,
    const float* __restrict__ aw1, const float* __restrict__ ab1,
    const float* __restrict__ aw2, const float* __restrict__ ab2,
    float* __restrict__ out_pa)
{
  __shared__ float s_w1[128][64];
  __shared__ float s_w2[64][3];
  __shared__ float s_b1[64];
  __shared__ float s_b2[3];
  __shared__ float s_f[NJ][NC];
  __shared__ float s_h[NJ][64];
  const int tid = threadIdx.x;
  const int lane = tid & 63, wave = tid >> 6;

  for (int i = tid; i < 128*64; i += 256) s_w1[i>>6][i&63] = aw1[i];
  if (tid < 64)  s_b1[tid] = ab1[tid];
  if (tid < 192) s_w2[tid/3][tid%3] = aw2[tid];
  if (tid < 3)   s_b2[tid] = ab2[tid];

  for (int fi = 0; fi < FPB2; ++fi){
    const long frame = (long)blockIdx.x * FPB2 + fi;
    __syncthreads();                       // protects s_f/s_h reuse + first-iter weights
    for (int i = tid; i < JC; i += 256) s_f[i>>7][i&127] = feat[frame*JC + i];
    __syncthreads();

    float a0=0.f, a1=0.f, a2=0.f, a3=0.f;
    const int j0 = wave * 4;
    for (int k = 0; k < 128; k += 4){
      const float4 f0 = *(const float4*)&s_f[j0+0][k];
      const float4 f1 = *(const float4*)&s_f[j0+1][k];
      const float4 f2 = *(const float4*)&s_f[j0+2][k];
      const float4 f3 = *(const float4*)&s_f[j0+3][k];
      #pragma unroll
      for (int s = 0; s < 4; ++s){
        const float w = s_w1[k+s][lane];
        a0 = fmaf(((const float*)&f0)[s], w, a0);
        a1 = fmaf(((const float*)&f1)[s], w, a1);
        a2 = fmaf(((const float*)&f2)[s], w, a2);
        a3 = fmaf(((const float*)&f3)[s], w, a3);
      }
    }
    s_h[j0+0][lane] = gelu_exact(a0 + s_b1[lane]);
    s_h[j0+1][lane] = gelu_exact(a1 + s_b1[lane]);
    s_h[j0+2][lane] = gelu_exact(a2 + s_b1[lane]);
    s_h[j0+3][lane] = gelu_exact(a3 + s_b1[lane]);
    if (wave == 0){
      float a4 = 0.f;
      for (int k = 0; k < 128; k += 4){
        const float4 fv = *(const float4*)&s_f[16][k];
        #pragma unroll
        for (int s = 0; s < 4; ++s)
          a4 = fmaf(((const float*)&fv)[s], s_w1[k+s][lane], a4);
      }
      s_h[16][lane] = gelu_exact(a4 + s_b1[lane]);
    }
    __syncthreads();
    if (tid < 51){
      const int jj = tid / 3, m = tid - jj*3;
      float s = s_b2[m];
      #pragma unroll 8
      for (int k = 0; k < 64; ++k) s = fmaf(s_h[jj][k], s_w2[k][m], s);
      out_pa[frame*51 + tid] = s;
    }
  }
}

// ---------------- bone MLP: relu(gelu(bonefeat@bw1+bb1)@bw2+bb2) ----------------
#define FPB3 2
template<int HALF, int RH, int NR>
__device__ __forceinline__ void bone_tile(float acc[FPB3][8],
    const float (&sf)[FPB3][NJ][NC], const float (&swt)[64][128],
    int n, int kbase)
{
  #pragma unroll
  for (int fi = 0; fi < FPB3; ++fi){
    #pragma unroll
    for (int k4 = 0; k4 < 16; ++k4){
      float4 fv[NR];
      #pragma unroll
      for (int i = 0; i < NR; ++i){
        const int r = 2*i + RH;
        const int j = HALF ? cB[r] : cA[r];
        fv[i] = *(const float4*)&sf[fi][j][kbase + k4*4];
      }
      #pragma unroll
      for (int s = 0; s < 4; ++s){
        const float w = swt[k4*4 + s][n];
        #pragma unroll
        for (int i = 0; i < NR; ++i)
          acc[fi][i] = fmaf(((const float*)&fv[i])[s], w, acc[fi][i]);
      }
    }
  }
}

template<int NR>
__device__ __forceinline__ void bone_epi(float acc[FPB3][8],
    float (&s_red)[4][FPB3][8], int wave, int lane, int n,
    const float* __restrict__ bb1, const float* __restrict__ bw2)
{
  const float b = bb1[n], w2 = bw2[n];
  #pragma unroll
  for (int fi = 0; fi < FPB3; ++fi){
    #pragma unroll
    for (int i = 0; i < NR; ++i){
      float p = gelu_exact(acc[fi][i] + b) * w2;
      #pragma unroll
      for (int off = 32; off > 0; off >>= 1) p += __shfl_xor(p, off);
      if (lane == 0) s_red[wave][fi][i] = p;
    }
  }
}

__global__ __launch_bounds__(256) void k_bone(const float* __restrict__ feat,
    const float* __restrict__ bw1, const float* __restrict__ bb1,
    const float* __restrict__ bw2, const float* __restrict__ bb2,
    float* __restrict__ out_pbl)
{
  __shared__ float s_wt[64][128];           // 32 KB K-tile of bw1
  __shared__ float s_f[FPB3][NJ][NC];       // 17 KB
  __shared__ float s_red[4][FPB3][8];
  const int tid = threadIdx.x;
  const int lane = tid & 63, wave = tid >> 6;
  const int n = tid & 127, rh = tid >> 7;
  const long f0 = (long)blockIdx.x * FPB3;

  for (int i = tid; i < FPB3*JC; i += 256){
    const int fi = i / JC, r = i - fi*JC;
    s_f[fi][r>>7][r&127] = feat[(f0 + fi)*JC + r];
  }

  float acc[FPB3][8];
  #pragma unroll
  for (int fi = 0; fi < FPB3; ++fi)
    #pragma unroll
    for (int i = 0; i < 8; ++i) acc[fi][i] = 0.0f;

  for (int kt = 0; kt < 4; ++kt){
    __syncthreads();
    for (int i = tid; i < 64*128; i += 256)
      s_wt[i>>7][i&127] = bw1[(kt*64 + (i>>7))*128 + (i&127)];
    __syncthreads();
    const int kbase = (kt & 1) * 64;
    if (kt < 2){
      if (rh == 0) bone_tile<0,0,8>(acc, s_f, s_wt, n, kbase);
      else         bone_tile<0,1,7>(acc, s_f, s_wt, n, kbase);
    } else {
      if (rh == 0) bone_tile<1,0,8>(acc, s_f, s_wt, n, kbase);
      else         bone_tile<1,1,7>(acc, s_f, s_wt, n, kbase);
    }
  }

  if (rh == 0) bone_epi<8>(acc, s_red, wave, lane, n, bb1, bw2);
  else         bone_epi<7>(acc, s_red, wave, lane, n, bb1, bw2);
  __syncthreads();
  if (tid < FPB3*15){
    const int fi = tid / 15, r = tid - fi*15;
    const int p2 = r & 1, i = r >> 1;
    const float v = s_red[2*p2][fi][i] + s_red[2*p2+1][fi][i] + bb2[0];
    out_pbl[(f0 + fi)*15 + r] = fmaxf(v, 0.0f);
  }
}

// ---------------- action classifier ----------------
__global__ __launch_bounds__(256) void k_mean(const float* __restrict__ feat,
                                              float* __restrict__ mean_ws)
{
  const int jc = blockIdx.x * 256 + threadIdx.x;
  const int b = blockIdx.y;
  if (jc >= JC) return;
  float s = 0.0f;
  const float* p = feat + (long)b * 243 * JC + jc;
  #pragma unroll 8
  for (int t = 0; t < 243; ++t) s += p[(long)t * JC];
  mean_ws[(long)b*JC + jc] = s * (1.0f/243.0f);
}

__global__ __launch_bounds__(256) void k_action(const float* __restrict__ mean_src,
    const float* __restrict__ cw1, const float* __restrict__ cb1,
    const float* __restrict__ cw2, const float* __restrict__ cb2,
    float* __restrict__ out_lg)
{
  __shared__ float s_m[JC];
  __shared__ float s_part[4][64];
  __shared__ float s_h[64];
  const int b = blockIdx.x, tid = threadIdx.x;
  for (int i = tid; i < JC; i += 256) s_m[i] = mean_src[(long)b*JC + i];
  __syncthreads();
  const int n = tid & 63, part = tid >> 6;
  float s = 0.0f;
  const int k0 = part * 544;
  for (int k = k0; k < k0 + 544; ++k) s = fmaf(s_m[k], cw1[(long)k*64 + n], s);
  s_part[part][n] = s;
  __syncthreads();
  if (tid < 64) s_h[tid] = gelu_exact(s_part[0][tid] + s_part[1][tid] +
                                      s_part[2][tid] + s_part[3][tid] + cb1[tid]);
  __syncthreads();
  if (tid < 8){
    float v = cb2[tid];
    #pragma unroll
    for (int k = 0; k < 64; ++k) v = fmaf(s_h[k], cw2[k*8 + tid], v);
    out_lg[b*8 + tid] = v;
  }
}

__global__ __launch_bounds__(256) void k_action_fused(const float* __restrict__ feat,
    const float* __restrict__ cw1, const float* __restrict__ cb1,
    const float* __restrict__ cw2, const float* __restrict__ cb2,
    float* __restrict__ out_lg)
{
  __shared__ float s_m[JC];
  __shared__ float s_part[4][64];
  __shared__ float s_h[64];
  const int b = blockIdx.x, tid = threadIdx.x;
  for (int jc = tid; jc < JC; jc += 256){
    float s = 0.0f;
    const float* p = feat + (long)b * 243 * JC + jc;
    for (int t = 0; t < 243; ++t) s += p[(long)t * JC];
    s_m[jc] = s * (1.0f/243.0f);
  }
  __syncthreads();
  const int n = tid & 63, part = tid >> 6;
  float s = 0.0f;
  const int k0 = part * 544;
  for (int k = k0; k < k0 + 544; ++k) s = fmaf(s_m[k], cw1[(long)k*64 + n], s);
  s_part[part][n] = s;
  __syncthreads();
  if (tid < 64) s_h[tid] = gelu_exact(s_part[0][tid] + s_part[1][tid] +
                                      s_part[2][tid] + s_part[3][tid] + cb1[tid]);
  __syncthreads();
  if (tid < 8){
    float v = cb2[tid];
    #pragma unroll
    for (int k = 0; k < 64; ++k) v = fmaf(s_h[k], cw2[k*8 + tid], v);
    out_lg[b*8 + tid] = v;
  }
}

extern "C" void kernel_launch(void* const* d_in, const int* in_sizes, int n_in,
                              void* d_out, int out_size, void* d_ws, size_t ws_size,
                              hipStream_t stream)
{
  const float* feat = (const float*)d_in[0];
  const float* pose = (const float*)d_in[1];
  const float* aw1  = (const float*)d_in[2];
  const float* ab1  = (const float*)d_in[3];
  const float* aw2  = (const float*)d_in[4];
  const float* ab2  = (const float*)d_in[5];
  const float* bw1  = (const float*)d_in[6];
  const float* bb1  = (const float*)d_in[7];
  const float* bw2  = (const float*)d_in[8];
  const float* bb2  = (const float*)d_in[9];
  const float* cw1  = (const float*)d_in[10];
  const float* cb1  = (const float*)d_in[11];
  const float* cw2  = (const float*)d_in[12];
  const float* cb2  = (const float*)d_in[13];

  float* out = (float*)d_out;
  float* out_pa  = out;                 // [NF,17,3]  793152
  float* out_aa  = out + 793152;        // [NF,17,1]  264384
  float* out_pbl = out + 1057536;       // [NF,15,1]  233280
  float* out_abl = out + 1290816;       // [NF,15,1]  233280
  float* out_lg  = out + 1524096;       // [64,8]     512

  k_geom<<<dim3((NF + 255)/256), dim3(256), 0, stream>>>(pose, out_aa, out_abl);
  k_angle<<<dim3(NF/FPB2), dim3(256), 0, stream>>>(feat, aw1, ab1, aw2, ab2, out_pa);
  k_bone<<<dim3(NF/FPB3), dim3(256), 0, stream>>>(feat, bw1, bb1, bw2, bb2, out_pbl);

  const size_t need = (size_t)64 * JC * sizeof(float);
  if (ws_size >= need){
    float* mean_ws = (float*)d_ws;
    k_mean<<<dim3((JC + 255)/256, 64), dim3(256), 0, stream>>>(feat, mean_ws);
    k_action<<<dim3(64), dim3(256), 0, stream>>>(mean_ws, cw1, cb1, cw2, cb2, out_lg);
  } else {
    k_action_fused<<<dim3(64), dim3(256), 0, stream>>>(feat, cw1, cb1, cw2, cb2, out_lg);
  }
}

// Round 2
// 598.348 us; speedup vs baseline: 2.7422x; 2.7422x over previous
//
#include <hip/hip_runtime.h>
#include <math.h>

#define NF 15552      // B*T
#define NJ 17
#define NC 128
#define JC (NJ*NC)    // 2176

constexpr int cA[15] = {0,1,2,0,4,5,0,7,8,0,10,11,0,13,14};
constexpr int cB[15] = {1,2,3,4,5,6,7,8,9,10,11,12,13,14,15};
constexpr int aJ[4] = {11,14,5,8};
constexpr int aP[4] = {10,13,4,7};
constexpr int aCc[4] = {12,15,6,9};

__device__ const int d_cA16[16] = {0,1,2,0,4,5,0,7,8,0,10,11,0,13,14,0};
__device__ const int d_cB16[16] = {1,2,3,4,5,6,7,8,9,10,11,12,13,14,15,0};

typedef __bf16 bf16x8 __attribute__((ext_vector_type(8)));
typedef float f32x4 __attribute__((ext_vector_type(4)));
typedef unsigned short u16x8 __attribute__((ext_vector_type(8)));
typedef unsigned short u16x4 __attribute__((ext_vector_type(4)));

__device__ __forceinline__ float gelu_exact(float x){
  return 0.5f * x * (1.0f + erff(x * 0.7071067811865476f));
}

__device__ __forceinline__ unsigned short f2bf(float f){
  unsigned u = __builtin_bit_cast(unsigned, f);
  unsigned r = (u + 0x7FFFu + ((u >> 16) & 1u)) >> 16;
  return (unsigned short)r;
}

// ---------------- geometry: actual_angles + actual_bone_lengths ----------------
__global__ __launch_bounds__(256) void k_geom(const float* __restrict__ pose,
                                              float* __restrict__ out_aa,
                                              float* __restrict__ out_abl)
{
  const int f = blockIdx.x * 256 + threadIdx.x;
  if (f >= NF) return;
  const float* p = pose + (long)f * NJ * 3;
  float px[NJ], py[NJ], pz[NJ];
  #pragma unroll
  for (int j = 0; j < NJ; ++j){ px[j] = p[3*j]; py[j] = p[3*j+1]; pz[j] = p[3*j+2]; }

  #pragma unroll
  for (int i = 0; i < 15; ++i){
    const int a = cA[i], b = cB[i];
    const float dx = px[b]-px[a], dy = py[b]-py[a], dz = pz[b]-pz[a];
    out_abl[(long)f*15 + i] = sqrtf(dx*dx + dy*dy + dz*dz);
  }

  float ang[NJ];
  #pragma unroll
  for (int j = 0; j < NJ; ++j) ang[j] = 0.0f;
  #pragma unroll
  for (int i = 0; i < 4; ++i){
    const int jj = aJ[i], pp = aP[i], cc = aCc[i];
    float v1x = px[jj]-px[pp], v1y = py[jj]-py[pp], v1z = pz[jj]-pz[pp];
    float v2x = px[cc]-px[jj], v2y = py[cc]-py[jj], v2z = pz[cc]-pz[jj];
    const float n1 = sqrtf(v1x*v1x + v1y*v1y + v1z*v1z) + 1e-10f;
    const float n2 = sqrtf(v2x*v2x + v2y*v2y + v2z*v2z) + 1e-10f;
    v1x /= n1; v1y /= n1; v1z /= n1;
    v2x /= n2; v2y /= n2; v2z /= n2;
    float d = v1x*v2x + v1y*v2y + v1z*v2z;
    d = fminf(fmaxf(d, -1.0f + 1e-7f), 1.0f - 1e-7f);
    ang[jj] = acosf(d);
  }
  #pragma unroll
  for (int j = 0; j < NJ; ++j) out_aa[(long)f*NJ + j] = ang[j];
}

// ---------------- angle MLP: gelu(f@aw1+ab1)@aw2+ab2 ----------------
#define FPB2 4
__global__ __launch_bounds__(256) void k_angle(const float* __restrict__ feat,
    const float* __restrict__ aw1, const float* __restrict__ ab1,
    const float* __restrict__ aw2, const float* __restrict__ ab2,
    float* __restrict__ out_pa)
{
  __shared__ float s_w1[128][64];
  __shared__ float s_w2[64][3];
  __shared__ float s_b1[64];
  __shared__ float s_b2[3];
  __shared__ float s_f[NJ][NC];
  __shared__ float s_h[NJ][64];
  const int tid = threadIdx.x;
  const int lane = tid & 63, wave = tid >> 6;

  for (int i = tid; i < 128*64; i += 256) s_w1[i>>6][i&63] = aw1[i];
  if (tid < 64)  s_b1[tid] = ab1[tid];
  if (tid < 192) s_w2[tid/3][tid%3] = aw2[tid];
  if (tid < 3)   s_b2[tid] = ab2[tid];

  for (int fi = 0; fi < FPB2; ++fi){
    const long frame = (long)blockIdx.x * FPB2 + fi;
    __syncthreads();
    for (int i = tid; i < JC; i += 256) s_f[i>>7][i&127] = feat[frame*JC + i];
    __syncthreads();

    float a0=0.f, a1=0.f, a2=0.f, a3=0.f;
    const int j0 = wave * 4;
    for (int k = 0; k < 128; k += 4){
      const float4 f0 = *(const float4*)&s_f[j0+0][k];
      const float4 f1 = *(const float4*)&s_f[j0+1][k];
      const float4 f2 = *(const float4*)&s_f[j0+2][k];
      const float4 f3 = *(const float4*)&s_f[j0+3][k];
      #pragma unroll
      for (int s = 0; s < 4; ++s){
        const float w = s_w1[k+s][lane];
        a0 = fmaf(((const float*)&f0)[s], w, a0);
        a1 = fmaf(((const float*)&f1)[s], w, a1);
        a2 = fmaf(((const float*)&f2)[s], w, a2);
        a3 = fmaf(((const float*)&f3)[s], w, a3);
      }
    }
    s_h[j0+0][lane] = gelu_exact(a0 + s_b1[lane]);
    s_h[j0+1][lane] = gelu_exact(a1 + s_b1[lane]);
    s_h[j0+2][lane] = gelu_exact(a2 + s_b1[lane]);
    s_h[j0+3][lane] = gelu_exact(a3 + s_b1[lane]);
    if (wave == 0){
      float a4 = 0.f;
      for (int k = 0; k < 128; k += 4){
        const float4 fv = *(const float4*)&s_f[16][k];
        #pragma unroll
        for (int s = 0; s < 4; ++s)
          a4 = fmaf(((const float*)&fv)[s], s_w1[k+s][lane], a4);
      }
      s_h[16][lane] = gelu_exact(a4 + s_b1[lane]);
    }
    __syncthreads();
    if (tid < 51){
      const int jj = tid / 3, m = tid - jj*3;
      float s = s_b2[m];
      #pragma unroll 8
      for (int k = 0; k < 64; ++k) s = fmaf(s_h[jj][k], s_w2[k][m], s);
      out_pa[frame*51 + tid] = s;
    }
  }
}

// ---------------- bone MLP via MFMA bf16 ----------------
// Per frame: M=16 padded bone rows (15 real), N=128 hidden, K=256.
// 4 waves split N (32 cols each, 2 n-frags); B (bw1) lives in 64 VGPRs/lane.
// feat staged per-frame in LDS as bf16 [17][136] (pad 8 breaks bank conflicts).
#define BFPI 4                 // frames per iteration
#define BITERS 2               // iterations per block
#define BFB (BFPI*BITERS)      // frames per block = 8
#define FSTRIDE 136
#define FELEMS (NJ*FSTRIDE)    // 2312 elems per frame

__global__ __launch_bounds__(256) void k_bone_mfma(const float* __restrict__ feat,
    const float* __restrict__ bw1, const float* __restrict__ bb1,
    const float* __restrict__ bw2, const float* __restrict__ bb2,
    float* __restrict__ out_pbl)
{
  __shared__ __align__(16) unsigned short s_feat[2][BFPI][NJ][FSTRIDE]; // 36992 B
  __shared__ float s_red[4][BFPI][16];                                  // 1 KB

  const int tid  = threadIdx.x;
  const int w    = tid >> 6;         // wave 0..3
  const int lane = tid & 63;
  const int g    = lane >> 4;        // k-group 0..3
  const int c    = lane & 15;        // bone row (A) / col-in-frag (B,D)
  const long f0  = (long)blockIdx.x * BFB;

  // ---- load B fragments of bw1 into registers (bf16), plus bb1/bw2 ----
  bf16x8 bfrag[8][2];
  float b1c[2], w2c[2];
  #pragma unroll
  for (int nf = 0; nf < 2; ++nf){
    const int col = w*32 + nf*16 + c;
    b1c[nf] = bb1[col];
    w2c[nf] = bw2[col];
    #pragma unroll
    for (int ks = 0; ks < 8; ++ks){
      u16x8 t;
      #pragma unroll
      for (int e = 0; e < 8; ++e)
        t[e] = f2bf(bw1[(ks*32 + g*8 + e)*128 + col]);
      bfrag[ks][nf] = __builtin_bit_cast(bf16x8, t);
    }
  }

  // ---- per-lane A-fragment LDS element offsets (within one frame buffer) ----
  const int jA = d_cA16[c], jB = d_cB16[c];
  int aoff[8];
  #pragma unroll
  for (int ks = 0; ks < 8; ++ks){
    const int kk = ks*32 + g*8;
    aoff[ks] = (kk < 128) ? (jA*FSTRIDE + kk) : (jB*FSTRIDE + (kk - 128));
  }

  // ---- staging helper (f32 global -> bf16 LDS), 544 float4 units/frame ----
  auto stage = [&](int buf, int it){
    unsigned short* dst = &s_feat[buf][0][0][0];
    const float* src = feat + (f0 + (long)it*BFPI) * JC;
    for (int u = tid; u < BFPI*544; u += 256){
      const int fi = u / 544, rem = u - fi*544;
      const int joint = rem >> 5, e4 = (rem & 31) << 2;
      const float4 v = *(const float4*)(src + (long)fi*JC + joint*128 + e4);
      u16x4 p; p[0]=f2bf(v.x); p[1]=f2bf(v.y); p[2]=f2bf(v.z); p[3]=f2bf(v.w);
      *(u16x4*)(dst + fi*FELEMS + joint*FSTRIDE + e4) = p;
    }
  };

  stage(0, 0);
  int buf = 0;

  for (int it = 0; it < BITERS; ++it){
    __syncthreads();                       // staged buf visible; s_red free
    if (it + 1 < BITERS) stage(buf ^ 1, it + 1);

    f32x4 acc[BFPI][2];
    #pragma unroll
    for (int fi = 0; fi < BFPI; ++fi){ acc[fi][0] = (f32x4)0.0f; acc[fi][1] = (f32x4)0.0f; }

    const unsigned short* fb = &s_feat[buf][0][0][0];
    #pragma unroll
    for (int ks = 0; ks < 8; ++ks){
      bf16x8 av[BFPI];
      #pragma unroll
      for (int fi = 0; fi < BFPI; ++fi)
        av[fi] = __builtin_bit_cast(bf16x8, *(const u16x8*)(fb + fi*FELEMS + aoff[ks]));
      #pragma unroll
      for (int fi = 0; fi < BFPI; ++fi){
        acc[fi][0] = __builtin_amdgcn_mfma_f32_16x16x32_bf16(av[fi], bfrag[ks][0], acc[fi][0], 0, 0, 0);
        acc[fi][1] = __builtin_amdgcn_mfma_f32_16x16x32_bf16(av[fi], bfrag[ks][1], acc[fi][1], 0, 0, 0);
      }
    }

    // ---- epilogue: gelu(h+b1)*w2, reduce over 128 cols ----
    #pragma unroll
    for (int fi = 0; fi < BFPI; ++fi){
      float s[4] = {0.f, 0.f, 0.f, 0.f};
      #pragma unroll
      for (int nf = 0; nf < 2; ++nf){
        #pragma unroll
        for (int r = 0; r < 4; ++r)
          s[r] += gelu_exact(acc[fi][nf][r] + b1c[nf]) * w2c[nf];
      }
      #pragma unroll
      for (int r = 0; r < 4; ++r){
        s[r] += __shfl_xor(s[r], 1);
        s[r] += __shfl_xor(s[r], 2);
        s[r] += __shfl_xor(s[r], 4);
        s[r] += __shfl_xor(s[r], 8);
      }
      if (c == 0){
        #pragma unroll
        for (int r = 0; r < 4; ++r) s_red[w][fi][g*4 + r] = s[r];
      }
    }
    __syncthreads();
    if (tid < BFPI*15){
      const int fi = tid / 15, row = tid - fi*15;
      const float v = s_red[0][fi][row] + s_red[1][fi][row] +
                      s_red[2][fi][row] + s_red[3][fi][row] + bb2[0];
      out_pbl[(f0 + (long)it*BFPI + fi)*15 + row] = fmaxf(v, 0.0f);
    }
    buf ^= 1;
  }
}

// ---------------- action classifier ----------------
__global__ __launch_bounds__(256) void k_mean(const float* __restrict__ feat,
                                              float* __restrict__ mean_ws)
{
  const int jc = blockIdx.x * 256 + threadIdx.x;
  const int b = blockIdx.y;
  if (jc >= JC) return;
  float s = 0.0f;
  const float* p = feat + (long)b * 243 * JC + jc;
  #pragma unroll 8
  for (int t = 0; t < 243; ++t) s += p[(long)t * JC];
  mean_ws[(long)b*JC + jc] = s * (1.0f/243.0f);
}

__global__ __launch_bounds__(256) void k_action(const float* __restrict__ mean_src,
    const float* __restrict__ cw1, const float* __restrict__ cb1,
    const float* __restrict__ cw2, const float* __restrict__ cb2,
    float* __restrict__ out_lg)
{
  __shared__ float s_m[JC];
  __shared__ float s_part[4][64];
  __shared__ float s_h[64];
  const int b = blockIdx.x, tid = threadIdx.x;
  for (int i = tid; i < JC; i += 256) s_m[i] = mean_src[(long)b*JC + i];
  __syncthreads();
  const int n = tid & 63, part = tid >> 6;
  float s = 0.0f;
  const int k0 = part * 544;
  for (int k = k0; k < k0 + 544; ++k) s = fmaf(s_m[k], cw1[(long)k*64 + n], s);
  s_part[part][n] = s;
  __syncthreads();
  if (tid < 64) s_h[tid] = gelu_exact(s_part[0][tid] + s_part[1][tid] +
                                      s_part[2][tid] + s_part[3][tid] + cb1[tid]);
  __syncthreads();
  if (tid < 8){
    float v = cb2[tid];
    #pragma unroll
    for (int k = 0; k < 64; ++k) v = fmaf(s_h[k], cw2[k*8 + tid], v);
    out_lg[b*8 + tid] = v;
  }
}

extern "C" void kernel_launch(void* const* d_in, const int* in_sizes, int n_in,
                              void* d_out, int out_size, void* d_ws, size_t ws_size,
                              hipStream_t stream)
{
  const float* feat = (const float*)d_in[0];
  const float* pose = (const float*)d_in[1];
  const float* aw1  = (const float*)d_in[2];
  const float* ab1  = (const float*)d_in[3];
  const float* aw2  = (const float*)d_in[4];
  const float* ab2  = (const float*)d_in[5];
  const float* bw1  = (const float*)d_in[6];
  const float* bb1  = (const float*)d_in[7];
  const float* bw2  = (const float*)d_in[8];
  const float* bb2  = (const float*)d_in[9];
  const float* cw1  = (const float*)d_in[10];
  const float* cb1  = (const float*)d_in[11];
  const float* cw2  = (const float*)d_in[12];
  const float* cb2  = (const float*)d_in[13];

  float* out = (float*)d_out;
  float* out_pa  = out;                 // [NF,17,3]  793152
  float* out_aa  = out + 793152;        // [NF,17,1]  264384
  float* out_pbl = out + 1057536;       // [NF,15,1]  233280
  float* out_abl = out + 1290816;       // [NF,15,1]  233280
  float* out_lg  = out + 1524096;       // [64,8]     512

  k_geom<<<dim3((NF + 255)/256), dim3(256), 0, stream>>>(pose, out_aa, out_abl);
  k_angle<<<dim3(NF/FPB2), dim3(256), 0, stream>>>(feat, aw1, ab1, aw2, ab2, out_pa);
  k_bone_mfma<<<dim3(NF/BFB), dim3(256), 0, stream>>>(feat, bw1, bb1, bw2, bb2, out_pbl);

  float* mean_ws = (float*)d_ws;
  k_mean<<<dim3((JC + 255)/256, 64), dim3(256), 0, stream>>>(feat, mean_ws);
  k_action<<<dim3(64), dim3(256), 0, stream>>>(mean_ws, cw1, cb1, cw2, cb2, out_lg);
}

// Round 3
// 169.822 us; speedup vs baseline: 9.6620x; 3.5234x over previous
//
#include <hip/hip_runtime.h>
#include <math.h>

#define NF 15552      // B*T
#define NJ 17
#define NC 128
#define JC (NJ*NC)    // 2176

constexpr int cA[15] = {0,1,2,0,4,5,0,7,8,0,10,11,0,13,14};
constexpr int cB[15] = {1,2,3,4,5,6,7,8,9,10,11,12,13,14,15};
constexpr int aJ[4] = {11,14,5,8};
constexpr int aP[4] = {10,13,4,7};
constexpr int aCc[4] = {12,15,6,9};

__device__ const int d_cA16[16] = {0,1,2,0,4,5,0,7,8,0,10,11,0,13,14,0};
__device__ const int d_cB16[16] = {1,2,3,4,5,6,7,8,9,10,11,12,13,14,15,0};

typedef __bf16 bf16x8 __attribute__((ext_vector_type(8)));
typedef float f32x4 __attribute__((ext_vector_type(4)));
typedef unsigned short u16x8 __attribute__((ext_vector_type(8)));
typedef unsigned short u16x4 __attribute__((ext_vector_type(4)));

__device__ __forceinline__ float gelu_exact(float x){
  return 0.5f * x * (1.0f + erff(x * 0.7071067811865476f));
}

__device__ __forceinline__ unsigned short f2bf(float f){
  unsigned u = __builtin_bit_cast(unsigned, f);
  unsigned r = (u + 0x7FFFu + ((u >> 16) & 1u)) >> 16;
  return (unsigned short)r;
}

// ---------------- geometry: actual_angles + actual_bone_lengths ----------------
__global__ __launch_bounds__(256) void k_geom(const float* __restrict__ pose,
                                              float* __restrict__ out_aa,
                                              float* __restrict__ out_abl)
{
  const int f = blockIdx.x * 256 + threadIdx.x;
  if (f >= NF) return;
  const float* p = pose + (long)f * NJ * 3;
  float px[NJ], py[NJ], pz[NJ];
  #pragma unroll
  for (int j = 0; j < NJ; ++j){ px[j] = p[3*j]; py[j] = p[3*j+1]; pz[j] = p[3*j+2]; }

  #pragma unroll
  for (int i = 0; i < 15; ++i){
    const int a = cA[i], b = cB[i];
    const float dx = px[b]-px[a], dy = py[b]-py[a], dz = pz[b]-pz[a];
    out_abl[(long)f*15 + i] = sqrtf(dx*dx + dy*dy + dz*dz);
  }

  float ang[NJ];
  #pragma unroll
  for (int j = 0; j < NJ; ++j) ang[j] = 0.0f;
  #pragma unroll
  for (int i = 0; i < 4; ++i){
    const int jj = aJ[i], pp = aP[i], cc = aCc[i];
    float v1x = px[jj]-px[pp], v1y = py[jj]-py[pp], v1z = pz[jj]-pz[pp];
    float v2x = px[cc]-px[jj], v2y = py[cc]-py[jj], v2z = pz[cc]-pz[jj];
    const float n1 = sqrtf(v1x*v1x + v1y*v1y + v1z*v1z) + 1e-10f;
    const float n2 = sqrtf(v2x*v2x + v2y*v2y + v2z*v2z) + 1e-10f;
    v1x /= n1; v1y /= n1; v1z /= n1;
    v2x /= n2; v2y /= n2; v2z /= n2;
    float d = v1x*v2x + v1y*v2y + v1z*v2z;
    d = fminf(fmaxf(d, -1.0f + 1e-7f), 1.0f - 1e-7f);
    ang[jj] = acosf(d);
  }
  #pragma unroll
  for (int j = 0; j < NJ; ++j) out_aa[(long)f*NJ + j] = ang[j];
}

// ---------------- angle MLP via MFMA bf16 ----------------
// Rows = NF*17 = 264384 flattened (frame,joint) rows. GEMM1: [rows,128]@[128,64],
// gelu, then [rows,64]@[64,3] done in-register (shuffle-reduce over 16 lanes).
// Per block: 4 waves x 16 rows = 64-row tiles, AITERS tiles.
#define AITERS 3
#define AROWS_PER_BLOCK (64*AITERS)   // 192
#define ASTRIDE 136                   // elems; 68 words = 4 mod 32 -> conflict-free b128

__global__ __launch_bounds__(256) void k_angle_mfma(const float* __restrict__ feat,
    const float* __restrict__ aw1, const float* __restrict__ ab1,
    const float* __restrict__ aw2, const float* __restrict__ ab2,
    float* __restrict__ out_pa)
{
  __shared__ __align__(16) unsigned short s_a[2][64][ASTRIDE];   // 34816 B

  const int tid  = threadIdx.x;
  const int w    = tid >> 6;
  const int lane = tid & 63;
  const int g    = lane >> 4;        // k-group / D-row-group
  const int c    = lane & 15;        // A row-in-frag / B,D col
  const long row0 = (long)blockIdx.x * AROWS_PER_BLOCK;

  // ---- B fragments of aw1 [128][64] in registers; epilogue constants ----
  bf16x8 bfrag[4][4];                // [kt][nf]
  float b1[4], w2c[4][3];
  #pragma unroll
  for (int nf = 0; nf < 4; ++nf){
    const int col = nf*16 + c;
    b1[nf] = ab1[col];
    #pragma unroll
    for (int m = 0; m < 3; ++m) w2c[nf][m] = aw2[col*3 + m];
    #pragma unroll
    for (int kt = 0; kt < 4; ++kt){
      u16x8 t;
      #pragma unroll
      for (int e = 0; e < 8; ++e)
        t[e] = f2bf(aw1[(kt*32 + g*8 + e)*64 + col]);
      bfrag[kt][nf] = __builtin_bit_cast(bf16x8, t);
    }
  }
  const float b2[3] = {ab2[0], ab2[1], ab2[2]};

  // ---- staging: 64 contiguous rows (f32 global -> bf16 LDS) ----
  auto stage = [&](int buf, int it){
    const float* src = feat + (row0 + (long)it*64) * NC;
    unsigned short* dst = &s_a[buf][0][0];
    #pragma unroll
    for (int u0 = 0; u0 < 2048; u0 += 256){
      const int u = u0 + tid;
      const int r = u >> 5, e4 = (u & 31) << 2;
      const float4 v = *(const float4*)(src + r*NC + e4);
      u16x4 p; p[0]=f2bf(v.x); p[1]=f2bf(v.y); p[2]=f2bf(v.z); p[3]=f2bf(v.w);
      *(u16x4*)(dst + r*ASTRIDE + e4) = p;
    }
  };

  stage(0, 0);
  int buf = 0;

  for (int it = 0; it < AITERS; ++it){
    __syncthreads();
    if (it + 1 < AITERS) stage(buf ^ 1, it + 1);

    f32x4 acc[4];
    #pragma unroll
    for (int nf = 0; nf < 4; ++nf) acc[nf] = (f32x4)0.0f;

    const unsigned short* ab = &s_a[buf][0][0];
    const int arow = w*16 + c;
    #pragma unroll
    for (int kt = 0; kt < 4; ++kt){
      const bf16x8 av = __builtin_bit_cast(bf16x8,
          *(const u16x8*)(ab + arow*ASTRIDE + kt*32 + g*8));
      #pragma unroll
      for (int nf = 0; nf < 4; ++nf)
        acc[nf] = __builtin_amdgcn_mfma_f32_16x16x32_bf16(av, bfrag[kt][nf], acc[nf], 0, 0, 0);
    }

    // ---- epilogue: gelu + [.,64]@[64,3] via lane reduce ----
    // D layout: lane (g,c) reg r holds D[row=g*4+r][col=nf*16+c]
    float s[4][3];
    #pragma unroll
    for (int r = 0; r < 4; ++r){ s[r][0]=0.f; s[r][1]=0.f; s[r][2]=0.f; }
    #pragma unroll
    for (int nf = 0; nf < 4; ++nf){
      #pragma unroll
      for (int r = 0; r < 4; ++r){
        const float h = gelu_exact(acc[nf][r] + b1[nf]);
        s[r][0] = fmaf(h, w2c[nf][0], s[r][0]);
        s[r][1] = fmaf(h, w2c[nf][1], s[r][1]);
        s[r][2] = fmaf(h, w2c[nf][2], s[r][2]);
      }
    }
    #pragma unroll
    for (int r = 0; r < 4; ++r){
      #pragma unroll
      for (int m = 0; m < 3; ++m){
        float v = s[r][m];
        v += __shfl_xor(v, 1);
        v += __shfl_xor(v, 2);
        v += __shfl_xor(v, 4);
        v += __shfl_xor(v, 8);
        s[r][m] = v;
      }
    }
    if (c == 0){
      const long grow = row0 + (long)it*64 + w*16 + g*4;
      #pragma unroll
      for (int r = 0; r < 4; ++r){
        #pragma unroll
        for (int m = 0; m < 3; ++m)
          out_pa[(grow + r)*3 + m] = s[r][m] + b2[m];
      }
    }
    buf ^= 1;
  }
}

// ---------------- bone MLP via MFMA bf16 ----------------
#define BFPI 4
#define BITERS 2
#define BFB (BFPI*BITERS)
#define FSTRIDE 136
#define FELEMS (NJ*FSTRIDE)

__global__ __launch_bounds__(256) void k_bone_mfma(const float* __restrict__ feat,
    const float* __restrict__ bw1, const float* __restrict__ bb1,
    const float* __restrict__ bw2, const float* __restrict__ bb2,
    float* __restrict__ out_pbl)
{
  __shared__ __align__(16) unsigned short s_feat[2][BFPI][NJ][FSTRIDE];
  __shared__ float s_red[4][BFPI][16];

  const int tid  = threadIdx.x;
  const int w    = tid >> 6;
  const int lane = tid & 63;
  const int g    = lane >> 4;
  const int c    = lane & 15;
  const long f0  = (long)blockIdx.x * BFB;

  bf16x8 bfrag[8][2];
  float b1c[2], w2c[2];
  #pragma unroll
  for (int nf = 0; nf < 2; ++nf){
    const int col = w*32 + nf*16 + c;
    b1c[nf] = bb1[col];
    w2c[nf] = bw2[col];
    #pragma unroll
    for (int ks = 0; ks < 8; ++ks){
      u16x8 t;
      #pragma unroll
      for (int e = 0; e < 8; ++e)
        t[e] = f2bf(bw1[(ks*32 + g*8 + e)*128 + col]);
      bfrag[ks][nf] = __builtin_bit_cast(bf16x8, t);
    }
  }

  const int jA = d_cA16[c], jB = d_cB16[c];
  int aoff[8];
  #pragma unroll
  for (int ks = 0; ks < 8; ++ks){
    const int kk = ks*32 + g*8;
    aoff[ks] = (kk < 128) ? (jA*FSTRIDE + kk) : (jB*FSTRIDE + (kk - 128));
  }

  auto stage = [&](int buf, int it){
    unsigned short* dst = &s_feat[buf][0][0][0];
    const float* src = feat + (f0 + (long)it*BFPI) * JC;
    for (int u = tid; u < BFPI*544; u += 256){
      const int fi = u / 544, rem = u - fi*544;
      const int joint = rem >> 5, e4 = (rem & 31) << 2;
      const float4 v = *(const float4*)(src + (long)fi*JC + joint*128 + e4);
      u16x4 p; p[0]=f2bf(v.x); p[1]=f2bf(v.y); p[2]=f2bf(v.z); p[3]=f2bf(v.w);
      *(u16x4*)(dst + fi*FELEMS + joint*FSTRIDE + e4) = p;
    }
  };

  stage(0, 0);
  int buf = 0;

  for (int it = 0; it < BITERS; ++it){
    __syncthreads();
    if (it + 1 < BITERS) stage(buf ^ 1, it + 1);

    f32x4 acc[BFPI][2];
    #pragma unroll
    for (int fi = 0; fi < BFPI; ++fi){ acc[fi][0] = (f32x4)0.0f; acc[fi][1] = (f32x4)0.0f; }

    const unsigned short* fb = &s_feat[buf][0][0][0];
    #pragma unroll
    for (int ks = 0; ks < 8; ++ks){
      bf16x8 av[BFPI];
      #pragma unroll
      for (int fi = 0; fi < BFPI; ++fi)
        av[fi] = __builtin_bit_cast(bf16x8, *(const u16x8*)(fb + fi*FELEMS + aoff[ks]));
      #pragma unroll
      for (int fi = 0; fi < BFPI; ++fi){
        acc[fi][0] = __builtin_amdgcn_mfma_f32_16x16x32_bf16(av[fi], bfrag[ks][0], acc[fi][0], 0, 0, 0);
        acc[fi][1] = __builtin_amdgcn_mfma_f32_16x16x32_bf16(av[fi], bfrag[ks][1], acc[fi][1], 0, 0, 0);
      }
    }

    #pragma unroll
    for (int fi = 0; fi < BFPI; ++fi){
      float s[4] = {0.f, 0.f, 0.f, 0.f};
      #pragma unroll
      for (int nf = 0; nf < 2; ++nf){
        #pragma unroll
        for (int r = 0; r < 4; ++r)
          s[r] += gelu_exact(acc[fi][nf][r] + b1c[nf]) * w2c[nf];
      }
      #pragma unroll
      for (int r = 0; r < 4; ++r){
        s[r] += __shfl_xor(s[r], 1);
        s[r] += __shfl_xor(s[r], 2);
        s[r] += __shfl_xor(s[r], 4);
        s[r] += __shfl_xor(s[r], 8);
      }
      if (c == 0){
        #pragma unroll
        for (int r = 0; r < 4; ++r) s_red[w][fi][g*4 + r] = s[r];
      }
    }
    __syncthreads();
    if (tid < BFPI*15){
      const int fi = tid / 15, row = tid - fi*15;
      const float v = s_red[0][fi][row] + s_red[1][fi][row] +
                      s_red[2][fi][row] + s_red[3][fi][row] + bb2[0];
      out_pbl[(f0 + (long)it*BFPI + fi)*15 + row] = fmaxf(v, 0.0f);
    }
    buf ^= 1;
  }
}

// ---------------- action classifier ----------------
__global__ __launch_bounds__(256) void k_mean(const float* __restrict__ feat,
                                              float* __restrict__ mean_ws)
{
  const int jc = blockIdx.x * 256 + threadIdx.x;
  const int b = blockIdx.y;
  if (jc >= JC) return;
  float s = 0.0f;
  const float* p = feat + (long)b * 243 * JC + jc;
  #pragma unroll 8
  for (int t = 0; t < 243; ++t) s += p[(long)t * JC];
  mean_ws[(long)b*JC + jc] = s * (1.0f/243.0f);
}

__global__ __launch_bounds__(256) void k_action(const float* __restrict__ mean_src,
    const float* __restrict__ cw1, const float* __restrict__ cb1,
    const float* __restrict__ cw2, const float* __restrict__ cb2,
    float* __restrict__ out_lg)
{
  __shared__ float s_m[JC];
  __shared__ float s_part[4][64];
  __shared__ float s_h[64];
  const int b = blockIdx.x, tid = threadIdx.x;
  for (int i = tid; i < JC; i += 256) s_m[i] = mean_src[(long)b*JC + i];
  __syncthreads();
  const int n = tid & 63, part = tid >> 6;
  float s = 0.0f;
  const int k0 = part * 544;
  for (int k = k0; k < k0 + 544; ++k) s = fmaf(s_m[k], cw1[(long)k*64 + n], s);
  s_part[part][n] = s;
  __syncthreads();
  if (tid < 64) s_h[tid] = gelu_exact(s_part[0][tid] + s_part[1][tid] +
                                      s_part[2][tid] + s_part[3][tid] + cb1[tid]);
  __syncthreads();
  if (tid < 8){
    float v = cb2[tid];
    #pragma unroll
    for (int k = 0; k < 64; ++k) v = fmaf(s_h[k], cw2[k*8 + tid], v);
    out_lg[b*8 + tid] = v;
  }
}

extern "C" void kernel_launch(void* const* d_in, const int* in_sizes, int n_in,
                              void* d_out, int out_size, void* d_ws, size_t ws_size,
                              hipStream_t stream)
{
  const float* feat = (const float*)d_in[0];
  const float* pose = (const float*)d_in[1];
  const float* aw1  = (const float*)d_in[2];
  const float* ab1  = (const float*)d_in[3];
  const float* aw2  = (const float*)d_in[4];
  const float* ab2  = (const float*)d_in[5];
  const float* bw1  = (const float*)d_in[6];
  const float* bb1  = (const float*)d_in[7];
  const float* bw2  = (const float*)d_in[8];
  const float* bb2  = (const float*)d_in[9];
  const float* cw1  = (const float*)d_in[10];
  const float* cb1  = (const float*)d_in[11];
  const float* cw2  = (const float*)d_in[12];
  const float* cb2  = (const float*)d_in[13];

  float* out = (float*)d_out;
  float* out_pa  = out;                 // [NF,17,3]  793152
  float* out_aa  = out + 793152;        // [NF,17,1]  264384
  float* out_pbl = out + 1057536;       // [NF,15,1]  233280
  float* out_abl = out + 1290816;       // [NF,15,1]  233280
  float* out_lg  = out + 1524096;       // [64,8]     512

  k_geom<<<dim3((NF + 255)/256), dim3(256), 0, stream>>>(pose, out_aa, out_abl);
  k_angle_mfma<<<dim3((NF*NJ)/AROWS_PER_BLOCK), dim3(256), 0, stream>>>(feat, aw1, ab1, aw2, ab2, out_pa);
  k_bone_mfma<<<dim3(NF/BFB), dim3(256), 0, stream>>>(feat, bw1, bb1, bw2, bb2, out_pbl);

  float* mean_ws = (float*)d_ws;
  k_mean<<<dim3((JC + 255)/256, 64), dim3(256), 0, stream>>>(feat, mean_ws);
  k_action<<<dim3(64), dim3(256), 0, stream>>>(mean_ws, cw1, cb1, cw2, cb2, out_lg);
}

// Round 4
// 146.918 us; speedup vs baseline: 11.1683x; 1.1559x over previous
//
#include <hip/hip_runtime.h>
#include <math.h>

#define NF 15552      // B*T
#define NJ 17
#define NC 128
#define JC (NJ*NC)    // 2176
#define TT 243        // frames per batch
#define FB 8          // frames per fused block

constexpr int cA[15] = {0,1,2,0,4,5,0,7,8,0,10,11,0,13,14};
constexpr int cB[15] = {1,2,3,4,5,6,7,8,9,10,11,12,13,14,15};
constexpr int aJ[4] = {11,14,5,8};
constexpr int aP[4] = {10,13,4,7};
constexpr int aCc[4] = {12,15,6,9};

__device__ const int d_cA16[16] = {0,1,2,0,4,5,0,7,8,0,10,11,0,13,14,0};
__device__ const int d_cB16[16] = {1,2,3,4,5,6,7,8,9,10,11,12,13,14,15,0};

typedef __bf16 bf16x8 __attribute__((ext_vector_type(8)));
typedef float f32x4 __attribute__((ext_vector_type(4)));
typedef unsigned short u16x8 __attribute__((ext_vector_type(8)));

__device__ __forceinline__ float gelu_exact(float x){
  return 0.5f * x * (1.0f + erff(x * 0.7071067811865476f));
}
// tanh-form gelu as x*sigmoid(x*(1.59577+0.071355x^2)); |err vs exact| <= ~3e-3
__device__ __forceinline__ float gelu_fast(float x){
  const float s2 = x * x;
  const float q  = fmaf(s2, -0.1029437f, -2.3021183f);   // -1.442695*(1.59577+0.071355 s2)
  const float e  = __builtin_amdgcn_exp2f(q * x);
  return x * __builtin_amdgcn_rcpf(1.0f + e);
}
__device__ __forceinline__ unsigned short bfc(float x){
  return __builtin_bit_cast(unsigned short, (__bf16)x);
}
__device__ __forceinline__ float bf2f(unsigned short u){
  return __builtin_bit_cast(float, ((unsigned)u) << 16);
}

// ---------------- geometry: actual_angles + actual_bone_lengths ----------------
__global__ __launch_bounds__(256) void k_geom(const float* __restrict__ pose,
                                              float* __restrict__ out_aa,
                                              float* __restrict__ out_abl)
{
  const int f = blockIdx.x * 256 + threadIdx.x;
  if (f >= NF) return;
  const float* p = pose + (long)f * NJ * 3;
  float px[NJ], py[NJ], pz[NJ];
  #pragma unroll
  for (int j = 0; j < NJ; ++j){ px[j] = p[3*j]; py[j] = p[3*j+1]; pz[j] = p[3*j+2]; }

  #pragma unroll
  for (int i = 0; i < 15; ++i){
    const int a = cA[i], b = cB[i];
    const float dx = px[b]-px[a], dy = py[b]-py[a], dz = pz[b]-pz[a];
    out_abl[(long)f*15 + i] = sqrtf(dx*dx + dy*dy + dz*dz);
  }

  float ang[NJ];
  #pragma unroll
  for (int j = 0; j < NJ; ++j) ang[j] = 0.0f;
  #pragma unroll
  for (int i = 0; i < 4; ++i){
    const int jj = aJ[i], pp = aP[i], cc = aCc[i];
    float v1x = px[jj]-px[pp], v1y = py[jj]-py[pp], v1z = pz[jj]-pz[pp];
    float v2x = px[cc]-px[jj], v2y = py[cc]-py[jj], v2z = pz[cc]-pz[jj];
    const float n1 = sqrtf(v1x*v1x + v1y*v1y + v1z*v1z) + 1e-10f;
    const float n2 = sqrtf(v2x*v2x + v2y*v2y + v2z*v2z) + 1e-10f;
    v1x /= n1; v1y /= n1; v1z /= n1;
    v2x /= n2; v2y /= n2; v2z /= n2;
    float d = v1x*v2x + v1y*v2y + v1z*v2z;
    d = fminf(fmaxf(d, -1.0f + 1e-7f), 1.0f - 1e-7f);
    ang[jj] = acosf(d);
  }
  #pragma unroll
  for (int j = 0; j < NJ; ++j) out_aa[(long)f*NJ + j] = ang[j];
}

// ---------------- fused: angle MLP + bone MLP + mean partial ----------------
// LDS tile: FB frames x 17 joints x 128 ch as bf16, stored in 16B blocks with
// T2-style swizzle: block index kb (0..15 within a row) stored at kb ^ (j&7).
// Element offset of (fi, j, k): SFO(fi, j*16 + ((k>>3)^(j&7)))*8 + (k&7).
#define SFO(fi, off16) (((fi)*272 + (off16))*8)

__global__ __launch_bounds__(256) void k_fused(const float* __restrict__ feat,
    const float* __restrict__ aw1, const float* __restrict__ ab1,
    const float* __restrict__ aw2, const float* __restrict__ ab2,
    const float* __restrict__ bw1, const float* __restrict__ bb1,
    const float* __restrict__ bw2, const float* __restrict__ bb2,
    float* __restrict__ out_pa, float* __restrict__ out_pbl,
    float* __restrict__ mean_acc)
{
  __shared__ __align__(16) unsigned short s_feat[FB*NJ*NC];   // 34816 B
  __shared__ float s_red[4][FB][16];                          // 2 KB

  const int tid  = threadIdx.x;
  const int w    = tid >> 6;
  const int lane = tid & 63;
  const int g    = lane >> 4;       // k-group
  const int c    = lane & 15;       // A-row / B,D-col within fragment
  const long f0  = (long)blockIdx.x * FB;

  // ---- stage FB frames f32 -> bf16 LDS (contiguous global reads) ----
  {
    const float* base = feat + f0 * JC;
    for (int u = tid; u < FB*272; u += 256){
      const float4 v0 = *(const float4*)(base + u*8);
      const float4 v1 = *(const float4*)(base + u*8 + 4);
      u16x8 p;
      p[0]=bfc(v0.x); p[1]=bfc(v0.y); p[2]=bfc(v0.z); p[3]=bfc(v0.w);
      p[4]=bfc(v1.x); p[5]=bfc(v1.y); p[6]=bfc(v1.z); p[7]=bfc(v1.w);
      const int fi = u / 272, r = u - fi*272;
      const int j = r >> 4, kb = r & 15;
      *(u16x8*)&s_feat[SFO(fi, j*16 + (kb ^ (j & 7)))] = p;
    }
  }

  // ---- bone weight fragments (bw1 [256][128]) ----
  bf16x8 wb[8][2];
  float bb1c[2], bw2c[2];
  #pragma unroll
  for (int nf = 0; nf < 2; ++nf){
    const int col = w*32 + nf*16 + c;
    bb1c[nf] = bb1[col];
    bw2c[nf] = bw2[col];
    #pragma unroll
    for (int ks = 0; ks < 8; ++ks){
      u16x8 t;
      #pragma unroll
      for (int e = 0; e < 8; ++e) t[e] = bfc(bw1[(ks*32 + g*8 + e)*128 + col]);
      wb[ks][nf] = __builtin_bit_cast(bf16x8, t);
    }
  }

  // ---- bone A-fragment LDS offsets (16B-block granular, swizzled) ----
  const int jA = d_cA16[c], jB = d_cB16[c];
  int boff[8];
  #pragma unroll
  for (int ks = 0; ks < 8; ++ks){
    const int kk = ks*32 + g*8;
    const int j  = (kk < 128) ? jA : jB;
    const int kb = (kk < 128) ? (ks*4 + g) : (ks*4 + g - 16);
    boff[ks] = j*16 + (kb ^ (j & 7));
  }

  __syncthreads();

  // ---- bone MFMA: M=16 bones, N=128 (wave splits), K=256, all FB frames ----
  f32x4 bacc[FB][2];
  #pragma unroll
  for (int fi = 0; fi < FB; ++fi){ bacc[fi][0] = (f32x4)0.0f; bacc[fi][1] = (f32x4)0.0f; }

  #pragma unroll
  for (int ks = 0; ks < 8; ++ks){
    bf16x8 av[FB];
    #pragma unroll
    for (int fi = 0; fi < FB; ++fi)
      av[fi] = __builtin_bit_cast(bf16x8, *(const u16x8*)&s_feat[SFO(fi, boff[ks])]);
    #pragma unroll
    for (int fi = 0; fi < FB; ++fi){
      bacc[fi][0] = __builtin_amdgcn_mfma_f32_16x16x32_bf16(av[fi], wb[ks][0], bacc[fi][0], 0, 0, 0);
      bacc[fi][1] = __builtin_amdgcn_mfma_f32_16x16x32_bf16(av[fi], wb[ks][1], bacc[fi][1], 0, 0, 0);
    }
  }

  // ---- bone epilogue: gelu(h+b1)*w2, reduce over this wave's 32 cols ----
  #pragma unroll
  for (int fi = 0; fi < FB; ++fi){
    float s[4] = {0.f, 0.f, 0.f, 0.f};
    #pragma unroll
    for (int nf = 0; nf < 2; ++nf)
      #pragma unroll
      for (int r = 0; r < 4; ++r)
        s[r] += gelu_fast(bacc[fi][nf][r] + bb1c[nf]) * bw2c[nf];
    #pragma unroll
    for (int r = 0; r < 4; ++r){
      s[r] += __shfl_xor(s[r], 1);
      s[r] += __shfl_xor(s[r], 2);
      s[r] += __shfl_xor(s[r], 4);
      s[r] += __shfl_xor(s[r], 8);
    }
    if (c == 0)
      #pragma unroll
      for (int r = 0; r < 4; ++r) s_red[w][fi][g*4 + r] = s[r];
  }

  // ---- angle phase: wave w handles frames 2w, 2w+1 (17 rows each) ----
  bf16x8 wa[4][4];
  float ab1c[4], aw2c[4][3];
  #pragma unroll
  for (int nf = 0; nf < 4; ++nf){
    const int col = nf*16 + c;
    ab1c[nf] = ab1[col];
    #pragma unroll
    for (int m = 0; m < 3; ++m) aw2c[nf][m] = aw2[col*3 + m];
    #pragma unroll
    for (int kt = 0; kt < 4; ++kt){
      u16x8 t;
      #pragma unroll
      for (int e = 0; e < 8; ++e) t[e] = bfc(aw1[(kt*32 + g*8 + e)*64 + col]);
      wa[kt][nf] = __builtin_bit_cast(bf16x8, t);
    }
  }
  const float ab2c[3] = {ab2[0], ab2[1], ab2[2]};

  const int fa0 = 2*w, fa1 = 2*w + 1;
  f32x4 acc0[4], acc1[4], accj[4];
  #pragma unroll
  for (int nf = 0; nf < 4; ++nf){ acc0[nf]=(f32x4)0.0f; acc1[nf]=(f32x4)0.0f; accj[nf]=(f32x4)0.0f; }

  #pragma unroll
  for (int kt = 0; kt < 4; ++kt){
    const int kbx = kt*4 + g;
    const bf16x8 av0 = __builtin_bit_cast(bf16x8,
        *(const u16x8*)&s_feat[SFO(fa0, c*16 + (kbx ^ (c & 7)))]);
    const bf16x8 av1 = __builtin_bit_cast(bf16x8,
        *(const u16x8*)&s_feat[SFO(fa1, c*16 + (kbx ^ (c & 7)))]);
    #pragma unroll
    for (int nf = 0; nf < 4; ++nf){
      acc0[nf] = __builtin_amdgcn_mfma_f32_16x16x32_bf16(av0, wa[kt][nf], acc0[nf], 0, 0, 0);
      acc1[nf] = __builtin_amdgcn_mfma_f32_16x16x32_bf16(av1, wa[kt][nf], acc1[nf], 0, 0, 0);
    }
    if (w == 0){
      const bf16x8 avj = __builtin_bit_cast(bf16x8,
          *(const u16x8*)&s_feat[SFO(c & 7, 16*16 + kbx)]);   // joint16, j&7==0
      #pragma unroll
      for (int nf = 0; nf < 4; ++nf)
        accj[nf] = __builtin_amdgcn_mfma_f32_16x16x32_bf16(avj, wa[kt][nf], accj[nf], 0, 0, 0);
    }
  }

  // angle epilogue: rows = joints (or frames for the j16 frag)
  #pragma unroll
  for (int half = 0; half < 2; ++half){
    const int fa = half ? fa1 : fa0;
    f32x4* acc = half ? acc1 : acc0;
    float s[4][3];
    #pragma unroll
    for (int r = 0; r < 4; ++r){ s[r][0]=0.f; s[r][1]=0.f; s[r][2]=0.f; }
    #pragma unroll
    for (int nf = 0; nf < 4; ++nf)
      #pragma unroll
      for (int r = 0; r < 4; ++r){
        const float h = gelu_fast(acc[nf][r] + ab1c[nf]);
        s[r][0] = fmaf(h, aw2c[nf][0], s[r][0]);
        s[r][1] = fmaf(h, aw2c[nf][1], s[r][1]);
        s[r][2] = fmaf(h, aw2c[nf][2], s[r][2]);
      }
    #pragma unroll
    for (int r = 0; r < 4; ++r)
      #pragma unroll
      for (int m = 0; m < 3; ++m){
        float v = s[r][m];
        v += __shfl_xor(v, 1);
        v += __shfl_xor(v, 2);
        v += __shfl_xor(v, 4);
        v += __shfl_xor(v, 8);
        s[r][m] = v;
      }
    if (c == 0){
      #pragma unroll
      for (int r = 0; r < 4; ++r){
        const long joint = g*4 + r;
        #pragma unroll
        for (int m = 0; m < 3; ++m)
          out_pa[((f0 + fa)*NJ + joint)*3 + m] = s[r][m] + ab2c[m];
      }
    }
  }
  if (w == 0){
    float s[4][3];
    #pragma unroll
    for (int r = 0; r < 4; ++r){ s[r][0]=0.f; s[r][1]=0.f; s[r][2]=0.f; }
    #pragma unroll
    for (int nf = 0; nf < 4; ++nf)
      #pragma unroll
      for (int r = 0; r < 4; ++r){
        const float h = gelu_fast(accj[nf][r] + ab1c[nf]);
        s[r][0] = fmaf(h, aw2c[nf][0], s[r][0]);
        s[r][1] = fmaf(h, aw2c[nf][1], s[r][1]);
        s[r][2] = fmaf(h, aw2c[nf][2], s[r][2]);
      }
    #pragma unroll
    for (int r = 0; r < 4; ++r)
      #pragma unroll
      for (int m = 0; m < 3; ++m){
        float v = s[r][m];
        v += __shfl_xor(v, 1);
        v += __shfl_xor(v, 2);
        v += __shfl_xor(v, 4);
        v += __shfl_xor(v, 8);
        s[r][m] = v;
      }
    if (c == 0 && g < 2){
      #pragma unroll
      for (int r = 0; r < 4; ++r){
        const long frame = g*4 + r;   // < 8
        #pragma unroll
        for (int m = 0; m < 3; ++m)
          out_pa[((f0 + frame)*NJ + 16)*3 + m] = s[r][m] + ab2c[m];
      }
    }
  }

  __syncthreads();   // s_red complete

  // ---- bone final cross-wave reduce ----
  if (tid < FB*15){
    const int fi = tid / 15, row = tid - fi*15;
    const float v = s_red[0][fi][row] + s_red[1][fi][row] +
                    s_red[2][fi][row] + s_red[3][fi][row] + bb2[0];
    out_pbl[(f0 + fi)*15 + row] = fmaxf(v, 0.0f);
  }

  // ---- mean partial: sum the FB staged frames, atomicAdd into mean_acc ----
  {
    const int b0 = (int)(f0 / TT);
    const int b1 = (int)((f0 + FB - 1) / TT);
    const int split = (b1 > b0) ? (b1*TT - (int)f0) : FB;
    for (int jc = tid; jc < JC; jc += 256){
      const int j = jc >> 7, k = jc & 127;
      const int eoff = (j*16 + ((k >> 3) ^ (j & 7)))*8 + (k & 7);
      float s0 = 0.f, s1 = 0.f;
      #pragma unroll
      for (int fi = 0; fi < FB; ++fi){
        const float v = bf2f(s_feat[fi*JC + eoff]);
        if (fi < split) s0 += v; else s1 += v;
      }
      atomicAdd(&mean_acc[(long)b0*JC + jc], s0);
      if (b1 > b0) atomicAdd(&mean_acc[(long)b1*JC + jc], s1);
    }
  }
}

// ---------------- action classifier (reads per-batch sums) ----------------
__global__ __launch_bounds__(256) void k_action(const float* __restrict__ sum_src,
    const float* __restrict__ cw1, const float* __restrict__ cb1,
    const float* __restrict__ cw2, const float* __restrict__ cb2,
    float* __restrict__ out_lg)
{
  __shared__ float s_m[JC];
  __shared__ float s_part[4][64];
  __shared__ float s_h[64];
  const int b = blockIdx.x, tid = threadIdx.x;
  for (int i = tid; i < JC; i += 256) s_m[i] = sum_src[(long)b*JC + i] * (1.0f/243.0f);
  __syncthreads();
  const int n = tid & 63, part = tid >> 6;
  float s = 0.0f;
  const int k0 = part * 544;
  for (int k = k0; k < k0 + 544; ++k) s = fmaf(s_m[k], cw1[(long)k*64 + n], s);
  s_part[part][n] = s;
  __syncthreads();
  if (tid < 64) s_h[tid] = gelu_exact(s_part[0][tid] + s_part[1][tid] +
                                      s_part[2][tid] + s_part[3][tid] + cb1[tid]);
  __syncthreads();
  if (tid < 8){
    float v = cb2[tid];
    #pragma unroll
    for (int k = 0; k < 64; ++k) v = fmaf(s_h[k], cw2[k*8 + tid], v);
    out_lg[b*8 + tid] = v;
  }
}

extern "C" void kernel_launch(void* const* d_in, const int* in_sizes, int n_in,
                              void* d_out, int out_size, void* d_ws, size_t ws_size,
                              hipStream_t stream)
{
  const float* feat = (const float*)d_in[0];
  const float* pose = (const float*)d_in[1];
  const float* aw1  = (const float*)d_in[2];
  const float* ab1  = (const float*)d_in[3];
  const float* aw2  = (const float*)d_in[4];
  const float* ab2  = (const float*)d_in[5];
  const float* bw1  = (const float*)d_in[6];
  const float* bb1  = (const float*)d_in[7];
  const float* bw2  = (const float*)d_in[8];
  const float* bb2  = (const float*)d_in[9];
  const float* cw1  = (const float*)d_in[10];
  const float* cb1  = (const float*)d_in[11];
  const float* cw2  = (const float*)d_in[12];
  const float* cb2  = (const float*)d_in[13];

  float* out = (float*)d_out;
  float* out_pa  = out;                 // [NF,17,3]  793152
  float* out_aa  = out + 793152;        // [NF,17,1]  264384
  float* out_pbl = out + 1057536;       // [NF,15,1]  233280
  float* out_abl = out + 1290816;       // [NF,15,1]  233280
  float* out_lg  = out + 1524096;       // [64,8]     512

  float* mean_acc = (float*)d_ws;       // 64*2176 f32 = 557056 B
  hipMemsetAsync(mean_acc, 0, (size_t)64 * JC * sizeof(float), stream);

  k_geom<<<dim3((NF + 255)/256), dim3(256), 0, stream>>>(pose, out_aa, out_abl);
  k_fused<<<dim3(NF/FB), dim3(256), 0, stream>>>(feat, aw1, ab1, aw2, ab2,
                                                 bw1, bb1, bw2, bb2,
                                                 out_pa, out_pbl, mean_acc);
  k_action<<<dim3(64), dim3(256), 0, stream>>>(mean_acc, cw1, cb1, cw2, cb2, out_lg);
}

// Round 5
// 145.134 us; speedup vs baseline: 11.3055x; 1.0123x over previous
//
#include <hip/hip_runtime.h>
#include <math.h>

#define NF 15552      // B*T
#define NJ 17
#define NC 128
#define JC (NJ*NC)    // 2176
#define TT 243        // frames per batch
#define FB 4          // frames per iteration
#define NIT 16        // iterations per block
#define FRB (FB*NIT)  // 64 frames per block; grid = NF/FRB = 243

constexpr int cA[15] = {0,1,2,0,4,5,0,7,8,0,10,11,0,13,14};
constexpr int cB[15] = {1,2,3,4,5,6,7,8,9,10,11,12,13,14,15};
constexpr int aJ[4] = {11,14,5,8};
constexpr int aP[4] = {10,13,4,7};
constexpr int aCc[4] = {12,15,6,9};

__device__ const int d_cA16[16] = {0,1,2,0,4,5,0,7,8,0,10,11,0,13,14,0};
__device__ const int d_cB16[16] = {1,2,3,4,5,6,7,8,9,10,11,12,13,14,15,0};

typedef __bf16 bf16x8 __attribute__((ext_vector_type(8)));
typedef float f32x4 __attribute__((ext_vector_type(4)));
typedef unsigned short u16x8 __attribute__((ext_vector_type(8)));

__device__ __forceinline__ float gelu_exact(float x){
  return 0.5f * x * (1.0f + erff(x * 0.7071067811865476f));
}
// tanh-form gelu; |err vs exact| <= ~3e-3
__device__ __forceinline__ float gelu_fast(float x){
  const float s2 = x * x;
  const float q  = fmaf(s2, -0.1029437f, -2.3021183f);
  const float e  = __builtin_amdgcn_exp2f(q * x);
  return x * __builtin_amdgcn_rcpf(1.0f + e);
}
__device__ __forceinline__ unsigned short bfc(float x){
  return __builtin_bit_cast(unsigned short, (__bf16)x);
}
__device__ __forceinline__ float bf2f(unsigned short u){
  return __builtin_bit_cast(float, ((unsigned)u) << 16);
}

// ---------------- geometry + mean_acc zeroing ----------------
__global__ __launch_bounds__(256) void k_geom(const float* __restrict__ pose,
                                              float* __restrict__ out_aa,
                                              float* __restrict__ out_abl,
                                              float* __restrict__ mean_acc)
{
  // zero the mean accumulator (64*JC floats) before k_fused's atomics
  for (long i = (long)blockIdx.x*256 + threadIdx.x; i < 64L*JC; i += (long)gridDim.x*256)
    mean_acc[i] = 0.0f;

  const int f = blockIdx.x * 256 + threadIdx.x;
  if (f >= NF) return;
  const float* p = pose + (long)f * NJ * 3;
  float px[NJ], py[NJ], pz[NJ];
  #pragma unroll
  for (int j = 0; j < NJ; ++j){ px[j] = p[3*j]; py[j] = p[3*j+1]; pz[j] = p[3*j+2]; }

  #pragma unroll
  for (int i = 0; i < 15; ++i){
    const int a = cA[i], b = cB[i];
    const float dx = px[b]-px[a], dy = py[b]-py[a], dz = pz[b]-pz[a];
    out_abl[(long)f*15 + i] = sqrtf(dx*dx + dy*dy + dz*dz);
  }

  float ang[NJ];
  #pragma unroll
  for (int j = 0; j < NJ; ++j) ang[j] = 0.0f;
  #pragma unroll
  for (int i = 0; i < 4; ++i){
    const int jj = aJ[i], pp = aP[i], cc = aCc[i];
    float v1x = px[jj]-px[pp], v1y = py[jj]-py[pp], v1z = pz[jj]-pz[pp];
    float v2x = px[cc]-px[jj], v2y = py[cc]-py[jj], v2z = pz[cc]-pz[jj];
    const float n1 = sqrtf(v1x*v1x + v1y*v1y + v1z*v1z) + 1e-10f;
    const float n2 = sqrtf(v2x*v2x + v2y*v2y + v2z*v2z) + 1e-10f;
    v1x /= n1; v1y /= n1; v1z /= n1;
    v2x /= n2; v2y /= n2; v2z /= n2;
    float d = v1x*v2x + v1y*v2y + v1z*v2z;
    d = fminf(fmaxf(d, -1.0f + 1e-7f), 1.0f - 1e-7f);
    ang[jj] = acosf(d);
  }
  #pragma unroll
  for (int j = 0; j < NJ; ++j) out_aa[(long)f*NJ + j] = ang[j];
}

// ---------------- fused: angle MLP + bone MLP + mean partial ----------------
// LDS: double-buffered FB frames x 17 x 128 bf16, 16B blocks swizzled kb^(j&7).
#define SFO(fi, off16) (((fi)*272 + (off16))*8)

__global__ __launch_bounds__(256, 1) void k_fused(const float* __restrict__ feat,
    const float* __restrict__ aw1, const float* __restrict__ ab1,
    const float* __restrict__ aw2, const float* __restrict__ ab2,
    const float* __restrict__ bw1, const float* __restrict__ bb1,
    const float* __restrict__ bw2, const float* __restrict__ bb2,
    float* __restrict__ out_pa, float* __restrict__ out_pbl,
    float* __restrict__ mean_acc)
{
  __shared__ __align__(16) unsigned short s_feat[2][FB*NJ*NC];  // 2x17408 B
  __shared__ float s_red[4][FB][16];                            // 1 KB

  const int tid  = threadIdx.x;
  const int w    = tid >> 6;
  const int lane = tid & 63;
  const int g    = lane >> 4;       // k-group
  const int c    = lane & 15;       // A-row / B,D-col within fragment
  const long F0  = (long)blockIdx.x * FRB;

  auto stage = [&](int bsel, int it){
    const float* base = feat + (F0 + (long)it*FB) * JC;
    unsigned short* dst = s_feat[bsel];
    #pragma unroll
    for (int u0 = 0; u0 < FB*272; u0 += 256){
      const int u = u0 + tid;
      if (u < FB*272){
        const float4 v0 = *(const float4*)(base + u*8);
        const float4 v1 = *(const float4*)(base + u*8 + 4);
        u16x8 p;
        p[0]=bfc(v0.x); p[1]=bfc(v0.y); p[2]=bfc(v0.z); p[3]=bfc(v0.w);
        p[4]=bfc(v1.x); p[5]=bfc(v1.y); p[6]=bfc(v1.z); p[7]=bfc(v1.w);
        const int fi = u / 272, r = u - fi*272;
        const int j = r >> 4, kb = r & 15;
        *(u16x8*)&dst[SFO(fi, j*16 + (kb ^ (j & 7)))] = p;
      }
    }
  };

  stage(0, 0);

  // ---- bone weight fragments (bw1 [256][128]) ----
  bf16x8 wb[8][2];
  float bb1c[2], bw2c[2];
  #pragma unroll
  for (int nf = 0; nf < 2; ++nf){
    const int col = w*32 + nf*16 + c;
    bb1c[nf] = bb1[col];
    bw2c[nf] = bw2[col];
    #pragma unroll
    for (int ks = 0; ks < 8; ++ks){
      u16x8 t;
      #pragma unroll
      for (int e = 0; e < 8; ++e) t[e] = bfc(bw1[(ks*32 + g*8 + e)*128 + col]);
      wb[ks][nf] = __builtin_bit_cast(bf16x8, t);
    }
  }
  // ---- angle weight fragments (aw1 [128][64]) ----
  bf16x8 wa[4][4];
  float ab1c[4], aw2c[4][3];
  #pragma unroll
  for (int nf = 0; nf < 4; ++nf){
    const int col = nf*16 + c;
    ab1c[nf] = ab1[col];
    #pragma unroll
    for (int m = 0; m < 3; ++m) aw2c[nf][m] = aw2[col*3 + m];
    #pragma unroll
    for (int kt = 0; kt < 4; ++kt){
      u16x8 t;
      #pragma unroll
      for (int e = 0; e < 8; ++e) t[e] = bfc(aw1[(kt*32 + g*8 + e)*64 + col]);
      wa[kt][nf] = __builtin_bit_cast(bf16x8, t);
    }
  }
  const float ab2c[3] = {ab2[0], ab2[1], ab2[2]};
  const float bb2c = bb2[0];

  // ---- bone A-fragment block offsets (swizzled) ----
  const int jA = d_cA16[c], jB = d_cB16[c];
  int boff[8];
  #pragma unroll
  for (int ks = 0; ks < 8; ++ks){
    const int kk = ks*32 + g*8;
    const int j  = (kk < 128) ? jA : jB;
    const int kb = (kk < 128) ? (ks*4 + g) : (ks*4 + g - 16);
    boff[ks] = j*16 + (kb ^ (j & 7));
  }

  // ---- mean accumulators (batch-split) ----
  const int b0    = (int)(F0 / TT);
  const int split = min(FRB, TT - (int)(F0 - (long)b0*TT));   // frames in batch b0
  float m0[9], m1[9];
  #pragma unroll
  for (int s = 0; s < 9; ++s){ m0[s] = 0.f; m1[s] = 0.f; }

  int buf = 0;
  for (int it = 0; it < NIT; ++it){
    __syncthreads();                       // staged buf ready; s_red free
    if (it + 1 < NIT) stage(buf ^ 1, it + 1);

    const unsigned short* fb = s_feat[buf];

    // ---- bone MFMA: all FB frames, this wave's 32 cols ----
    f32x4 bacc[FB][2];
    #pragma unroll
    for (int fi = 0; fi < FB; ++fi){ bacc[fi][0] = (f32x4)0.0f; bacc[fi][1] = (f32x4)0.0f; }
    #pragma unroll
    for (int ks = 0; ks < 8; ++ks){
      bf16x8 av[FB];
      #pragma unroll
      for (int fi = 0; fi < FB; ++fi)
        av[fi] = __builtin_bit_cast(bf16x8, *(const u16x8*)&fb[SFO(fi, boff[ks])]);
      #pragma unroll
      for (int fi = 0; fi < FB; ++fi){
        bacc[fi][0] = __builtin_amdgcn_mfma_f32_16x16x32_bf16(av[fi], wb[ks][0], bacc[fi][0], 0, 0, 0);
        bacc[fi][1] = __builtin_amdgcn_mfma_f32_16x16x32_bf16(av[fi], wb[ks][1], bacc[fi][1], 0, 0, 0);
      }
    }
    #pragma unroll
    for (int fi = 0; fi < FB; ++fi){
      float s[4] = {0.f, 0.f, 0.f, 0.f};
      #pragma unroll
      for (int nf = 0; nf < 2; ++nf)
        #pragma unroll
        for (int r = 0; r < 4; ++r)
          s[r] += gelu_fast(bacc[fi][nf][r] + bb1c[nf]) * bw2c[nf];
      #pragma unroll
      for (int r = 0; r < 4; ++r){
        s[r] += __shfl_xor(s[r], 1);
        s[r] += __shfl_xor(s[r], 2);
        s[r] += __shfl_xor(s[r], 4);
        s[r] += __shfl_xor(s[r], 8);
      }
      if (c == 0)
        #pragma unroll
        for (int r = 0; r < 4; ++r) s_red[w][fi][g*4 + r] = s[r];
    }

    // ---- angle MFMA: wave w -> frame w (16 joints); w0 also joint-16 rows ----
    f32x4 acc0[4], accj[4];
    #pragma unroll
    for (int nf = 0; nf < 4; ++nf){ acc0[nf]=(f32x4)0.0f; accj[nf]=(f32x4)0.0f; }
    #pragma unroll
    for (int kt = 0; kt < 4; ++kt){
      const int kbx = kt*4 + g;
      const bf16x8 av0 = __builtin_bit_cast(bf16x8,
          *(const u16x8*)&fb[SFO(w, c*16 + (kbx ^ (c & 7)))]);
      #pragma unroll
      for (int nf = 0; nf < 4; ++nf)
        acc0[nf] = __builtin_amdgcn_mfma_f32_16x16x32_bf16(av0, wa[kt][nf], acc0[nf], 0, 0, 0);
      if (w == 0){
        const bf16x8 avj = __builtin_bit_cast(bf16x8,
            *(const u16x8*)&fb[SFO(c & 3, 16*16 + kbx)]);   // joint 16 (j&7==0)
        #pragma unroll
        for (int nf = 0; nf < 4; ++nf)
          accj[nf] = __builtin_amdgcn_mfma_f32_16x16x32_bf16(avj, wa[kt][nf], accj[nf], 0, 0, 0);
      }
    }
    {
      float s[4][3];
      #pragma unroll
      for (int r = 0; r < 4; ++r){ s[r][0]=0.f; s[r][1]=0.f; s[r][2]=0.f; }
      #pragma unroll
      for (int nf = 0; nf < 4; ++nf)
        #pragma unroll
        for (int r = 0; r < 4; ++r){
          const float h = gelu_fast(acc0[nf][r] + ab1c[nf]);
          s[r][0] = fmaf(h, aw2c[nf][0], s[r][0]);
          s[r][1] = fmaf(h, aw2c[nf][1], s[r][1]);
          s[r][2] = fmaf(h, aw2c[nf][2], s[r][2]);
        }
      #pragma unroll
      for (int r = 0; r < 4; ++r)
        #pragma unroll
        for (int m = 0; m < 3; ++m){
          float v = s[r][m];
          v += __shfl_xor(v, 1);
          v += __shfl_xor(v, 2);
          v += __shfl_xor(v, 4);
          v += __shfl_xor(v, 8);
          s[r][m] = v;
        }
      if (c == 0){
        const long frame = F0 + (long)it*FB + w;
        #pragma unroll
        for (int r = 0; r < 4; ++r){
          const int joint = g*4 + r;
          #pragma unroll
          for (int m = 0; m < 3; ++m)
            out_pa[(frame*NJ + joint)*3 + m] = s[r][m] + ab2c[m];
        }
      }
    }
    if (w == 0){
      float s[4][3];
      #pragma unroll
      for (int r = 0; r < 4; ++r){ s[r][0]=0.f; s[r][1]=0.f; s[r][2]=0.f; }
      #pragma unroll
      for (int nf = 0; nf < 4; ++nf)
        #pragma unroll
        for (int r = 0; r < 4; ++r){
          const float h = gelu_fast(accj[nf][r] + ab1c[nf]);
          s[r][0] = fmaf(h, aw2c[nf][0], s[r][0]);
          s[r][1] = fmaf(h, aw2c[nf][1], s[r][1]);
          s[r][2] = fmaf(h, aw2c[nf][2], s[r][2]);
        }
      #pragma unroll
      for (int r = 0; r < 4; ++r)
        #pragma unroll
        for (int m = 0; m < 3; ++m){
          float v = s[r][m];
          v += __shfl_xor(v, 1);
          v += __shfl_xor(v, 2);
          v += __shfl_xor(v, 4);
          v += __shfl_xor(v, 8);
          s[r][m] = v;
        }
      if (c == 0 && g == 0){
        #pragma unroll
        for (int r = 0; r < 4; ++r){     // r = frame within iter
          const long frame = F0 + (long)it*FB + r;
          #pragma unroll
          for (int m = 0; m < 3; ++m)
            out_pa[(frame*NJ + 16)*3 + m] = s[r][m] + ab2c[m];
        }
      }
    }

    // ---- mean accumulate from staged tile ----
    #pragma unroll
    for (int s = 0; s < 9; ++s){
      const int jc = tid + s*256;
      if (jc < JC){
        const int j = jc >> 7, k = jc & 127;
        const int eoff = (j*16 + ((k >> 3) ^ (j & 7)))*8 + (k & 7);
        #pragma unroll
        for (int fi = 0; fi < FB; ++fi){
          const float v = bf2f(fb[fi*JC + eoff]);
          if (it*FB + fi < split) m0[s] += v; else m1[s] += v;
        }
      }
    }

    __syncthreads();                     // s_red complete
    if (tid < FB*15){
      const int fi = tid / 15, row = tid - fi*15;
      const float v = s_red[0][fi][row] + s_red[1][fi][row] +
                      s_red[2][fi][row] + s_red[3][fi][row] + bb2c;
      out_pbl[(F0 + (long)it*FB + fi)*15 + row] = fmaxf(v, 0.0f);
    }
    buf ^= 1;
  }

  // ---- mean flush: one atomic per (batch, jc) ----
  #pragma unroll
  for (int s = 0; s < 9; ++s){
    const int jc = tid + s*256;
    if (jc < JC){
      atomicAdd(&mean_acc[(long)b0*JC + jc], m0[s]);
      if (split < FRB) atomicAdd(&mean_acc[(long)(b0+1)*JC + jc], m1[s]);
    }
  }
}

// ---------------- action classifier (reads per-batch sums) ----------------
__global__ __launch_bounds__(256) void k_action(const float* __restrict__ sum_src,
    const float* __restrict__ cw1, const float* __restrict__ cb1,
    const float* __restrict__ cw2, const float* __restrict__ cb2,
    float* __restrict__ out_lg)
{
  __shared__ float s_m[JC];
  __shared__ float s_part[4][64];
  __shared__ float s_h[64];
  const int b = blockIdx.x, tid = threadIdx.x;
  for (int i = tid; i < JC; i += 256) s_m[i] = sum_src[(long)b*JC + i] * (1.0f/243.0f);
  __syncthreads();
  const int n = tid & 63, part = tid >> 6;
  float s = 0.0f;
  const int k0 = part * 544;
  for (int k = k0; k < k0 + 544; ++k) s = fmaf(s_m[k], cw1[(long)k*64 + n], s);
  s_part[part][n] = s;
  __syncthreads();
  if (tid < 64) s_h[tid] = gelu_exact(s_part[0][tid] + s_part[1][tid] +
                                      s_part[2][tid] + s_part[3][tid] + cb1[tid]);
  __syncthreads();
  if (tid < 8){
    float v = cb2[tid];
    #pragma unroll
    for (int k = 0; k < 64; ++k) v = fmaf(s_h[k], cw2[k*8 + tid], v);
    out_lg[b*8 + tid] = v;
  }
}

extern "C" void kernel_launch(void* const* d_in, const int* in_sizes, int n_in,
                              void* d_out, int out_size, void* d_ws, size_t ws_size,
                              hipStream_t stream)
{
  const float* feat = (const float*)d_in[0];
  const float* pose = (const float*)d_in[1];
  const float* aw1  = (const float*)d_in[2];
  const float* ab1  = (const float*)d_in[3];
  const float* aw2  = (const float*)d_in[4];
  const float* ab2  = (const float*)d_in[5];
  const float* bw1  = (const float*)d_in[6];
  const float* bb1  = (const float*)d_in[7];
  const float* bw2  = (const float*)d_in[8];
  const float* bb2  = (const float*)d_in[9];
  const float* cw1  = (const float*)d_in[10];
  const float* cb1  = (const float*)d_in[11];
  const float* cw2  = (const float*)d_in[12];
  const float* cb2  = (const float*)d_in[13];

  float* out = (float*)d_out;
  float* out_pa  = out;                 // [NF,17,3]  793152
  float* out_aa  = out + 793152;        // [NF,17,1]  264384
  float* out_pbl = out + 1057536;       // [NF,15,1]  233280
  float* out_abl = out + 1290816;       // [NF,15,1]  233280
  float* out_lg  = out + 1524096;       // [64,8]     512

  float* mean_acc = (float*)d_ws;       // 64*2176 f32

  k_geom<<<dim3((NF + 255)/256), dim3(256), 0, stream>>>(pose, out_aa, out_abl, mean_acc);
  k_fused<<<dim3(NF/FRB), dim3(256), 0, stream>>>(feat, aw1, ab1, aw2, ab2,
                                                  bw1, bb1, bw2, bb2,
                                                  out_pa, out_pbl, mean_acc);
  k_action<<<dim3(64), dim3(256), 0, stream>>>(mean_acc, cw1, cb1, cw2, cb2, out_lg);
}